// Round 6
// baseline (242.993 us; speedup 1.0000x reference)
//
#include <hip/hip_runtime.h>
#include <stdint.h>

// ---------------- problem constants ----------------
#define HW_      102400          // 320*320
#define C_       256
#define N_       1024
#define P_       2               // pairs
#define TILES_   1600            // 64-px tiles per src plane
#define CHUNKS_  64              // chunks per (pair, n-block)
#define CHUNK_PX 1600            // 25 tiles of 64 px
#define ITERS_   25
#define NB_      8               // n-blocks of 128 keypoints
#define K2_      144.269504088896340f   // 100 / ln(2)
#define MOFF_    (-72.134752044448170f) // -K2_ * 0.5 (fixed softmax max, cosine logits <= ~1.02)

typedef __attribute__((ext_vector_type(8))) short bf16x8;
typedef __attribute__((ext_vector_type(4))) float f32x4;

// ws layout (bytes):
//   tgt bf16 : [0, 1048576)        2*1024*256 bf16, [p][n][c]
//   partials : [1048576, 5242880)  2*64*2*1024 float4 (S,U,V,-)
//   PN       : [5242880, +100MB)   normalized src as bf16, [p][tile][r][dphys] dwords,
//              dphys = dlog ^ SW(r); dword = channels (2*dlog, 2*dlog+1), low = even ch
#define WS_TGT_OFF  0
#define WS_PAR_OFF  1048576
#define WS_PN_OFF   5242880

#define SWR(r) (((r) ^ ((r) >> 3)) & 7)   // swizzle (in 4-dword groups)

__device__ __forceinline__ uint32_t packbf(float a, float b) {
  uint32_t r;
  asm("v_cvt_pk_bf16_f32 %0, %1, %2" : "=v"(r) : "v"(a), "v"(b));
  return r;
}
__device__ __forceinline__ float fexp2(float x) {
  return __builtin_amdgcn_exp2f(x);
}
__device__ __forceinline__ void dma16(const uint32_t* g, uint32_t* l) {
  // async global->LDS, 16B per lane; LDS dest = wave-uniform base + lane*16
  __builtin_amdgcn_global_load_lds(
      (const __attribute__((address_space(1))) uint32_t*)g,
      (__attribute__((address_space(3))) uint32_t*)l, 16, 0, 0);
}

// ---------------- kernel 1: (a) prenorm dense -> PN (bf16, swizzled); (b) tgt normalize ----------------
__global__ __launch_bounds__(256)
void k_pre(const float* __restrict__ dense, const float* __restrict__ kdesc,
           const float* __restrict__ kscores, uint32_t* __restrict__ PN,
           uint16_t* __restrict__ tgt, float* __restrict__ out) {
  const int bid = blockIdx.x;
  if (bid < P_ * TILES_) {
    // ---- prenorm: block = one 64-px tile; wave cq owns channels cq*64..+63, lane = px row r ----
    const int p = bid / TILES_, tile = bid % TILES_;
    const int r  = threadIdx.x & 63;
    const int cq = threadIdx.x >> 6;
    const float* src = dense + (size_t)(p * 2) * C_ * HW_ + (size_t)(cq * 64) * HW_
                     + tile * 64 + r;                       // src ids 0,2
    float v[64];
    #pragma unroll
    for (int c = 0; c < 64; ++c) v[c] = src[(size_t)c * HW_];
    float s0 = 0.f, s1 = 0.f, s2 = 0.f, s3 = 0.f;
    #pragma unroll
    for (int c = 0; c < 64; c += 4) {
      s0 = fmaf(v[c + 0], v[c + 0], s0);
      s1 = fmaf(v[c + 1], v[c + 1], s1);
      s2 = fmaf(v[c + 2], v[c + 2], s2);
      s3 = fmaf(v[c + 3], v[c + 3], s3);
    }
    __shared__ float part[4][64];
    __shared__ float sinv[64];
    part[cq][r] = (s0 + s1) + (s2 + s3);
    __syncthreads();
    if (threadIdx.x < 64) {
      const float s = part[0][threadIdx.x] + part[1][threadIdx.x]
                    + part[2][threadIdx.x] + part[3][threadIdx.x];
      sinv[threadIdx.x] = 1.f / fmaxf(sqrtf(s), 1e-12f);
    }
    __syncthreads();
    const float inv = sinv[r];
    const int s8 = SWR(r);
    uint32_t* dst = PN + ((size_t)(p * TILES_ + tile) << 13) + r * 128 + cq * 32;
    // register-group rg (channels 8rg..+7, static indices) -> phys group rg^s8 (runtime addr)
    #pragma unroll
    for (int rg = 0; rg < 8; ++rg) {
      uint4 wv;
      wv.x = packbf(v[rg * 8 + 0] * inv, v[rg * 8 + 1] * inv);
      wv.y = packbf(v[rg * 8 + 2] * inv, v[rg * 8 + 3] * inv);
      wv.z = packbf(v[rg * 8 + 4] * inv, v[rg * 8 + 5] * inv);
      wv.w = packbf(v[rg * 8 + 6] * inv, v[rg * 8 + 7] * inv);
      *(uint4*)&dst[(rg ^ s8) << 2] = wv;
    }
  } else {
    // ---- tgt keypoint descriptors -> normalized bf16 [p][n][c]; copy weights ----
    const int t = (bid - P_ * TILES_) * 256 + threadIdx.x;   // 0..2047
    const int p = t >> 10, n = t & 1023;
    const float* src = kdesc + (size_t)(p * 2 + 1) * C_ * N_ + n;   // tgt ids 1,3
    float s = 0.f;
    #pragma unroll 16
    for (int c = 0; c < C_; ++c) { const float v = src[c * N_]; s = fmaf(v, v, s); }
    const float inv = 1.f / fmaxf(sqrtf(s), 1e-12f);
    uint32_t* dst = (uint32_t*)(tgt + (size_t)t * C_);
    #pragma unroll 4
    for (int c8 = 0; c8 < C_; c8 += 8) {
      uint4 wv;
      wv.x = packbf(src[(c8 + 0) * N_] * inv, src[(c8 + 1) * N_] * inv);
      wv.y = packbf(src[(c8 + 2) * N_] * inv, src[(c8 + 3) * N_] * inv);
      wv.z = packbf(src[(c8 + 4) * N_] * inv, src[(c8 + 5) * N_] * inv);
      wv.w = packbf(src[(c8 + 6) * N_] * inv, src[(c8 + 7) * N_] * inv);
      *(uint4*)&dst[c8 / 2] = wv;
    }
    out[4096 + t] = kscores[(p * 2 + 1) * N_ + n];   // match_weights
  }
}

// ---------------- kernel 2: DMA-staged QK^T + fixed-max softmax + soft-argmax ----------------
// block: 512 thr (8 waves = 2(h) x 4(q)); 128 keypoints x 1600 px chunk. grid 1024.
// T3/T4-lite pipeline: raw s_barrier + COUNTED vmcnt(4) -- next tile's DMAs stay in flight
// across barriers, no vmcnt(0) drain in the main loop. T5 setprio around the MFMA cluster.
// The 8 blocks sharing a (p,chunk) map to the SAME XCD (bids differ by 8 under round-robin).
__global__ __launch_bounds__(512, 3)
void k_main(const uint32_t* __restrict__ PN, const uint16_t* __restrict__ tgt,
            float4* __restrict__ partials) {
  __shared__ uint32_t lds[2 * 64 * 128];   // 2 bufs x (64 px x 256 bf16) = 64 KB

  const int bid = blockIdx.x;              // 0..1023
  const int xcd = bid & 7;
  const int rr  = bid >> 3;                // 0..127
  const int nb  = rr & 7;
  const int grp = xcd + 8 * (rr >> 3);     // 0..127 = (p, chunk)
  const int p     = grp >> 6;
  const int chunk = grp & 63;

  const int t    = threadIdx.x;
  const int lane = t & 63;
  const int w    = t >> 6;
  const int l15  = lane & 15;
  const int g4   = lane >> 4;
  const int h    = w & 1;    // px half (32 rows)
  const int q    = w >> 1;   // n quarter (32 n)

  // ---- B fragments (tgt, [n][c] bf16): 2 j-tiles x 8 k-slices = 64 VGPR ----
  bf16x8 Bf[2][8];
  const int nbase = nb * 128 + q * 32;
  #pragma unroll
  for (int j = 0; j < 2; ++j) {
    const uint16_t* tp = tgt + (size_t)(p * N_ + nbase + j * 16 + l15) * C_ + g4 * 8;
    #pragma unroll
    for (int k = 0; k < 8; ++k) Bf[j][k] = *(const bf16x8*)(tp + k * 32);
  }

  float stS[2], stU[2], stV[2];
  #pragma unroll
  for (int j = 0; j < 2; ++j) { stS[j] = 0.f; stU[j] = 0.f; stV[j] = 0.f; }

  const int row0  = h * 32 + l15;
  const int row1  = row0 + 16;
  const int sw0   = SWR(row0) << 2;
  const int sw1   = SWR(row1) << 2;
  const int base0 = row0 * 128;
  const int base1 = row1 * 128;
  const int lr0   = h * 32 + g4 * 4;       // acc row base (s=0)

  // DMA: wave w stages 4KB of the 32KB tile; source is contiguous (pre-permuted by k_pre)
  const uint32_t* PNp = PN + ((size_t)(p * TILES_ + chunk * 25) << 13) + w * 1024 + lane * 4;
  uint32_t* ldsw = &lds[w * 1024];

  // ---- prologue: stage tiles 0 and 1; wait only for tile 0 (counted) ----
  #pragma unroll
  for (int jj = 0; jj < 4; ++jj) dma16(PNp + jj * 256, ldsw + jj * 256);
  #pragma unroll
  for (int jj = 0; jj < 4; ++jj) dma16(PNp + 8192 + jj * 256, ldsw + 8192 + jj * 256);
  asm volatile("s_waitcnt vmcnt(4)" ::: "memory");   // own tile-0 loads done
  __builtin_amdgcn_sched_barrier(0);
  __builtin_amdgcn_s_barrier();                      // all waves' tile-0 loads done

  for (int iter = 0; iter < ITERS_; ++iter) {
    const uint32_t* bufR = &lds[(iter & 1) * 8192];

    // ---- MFMA from bufR ----
    f32x4 acc[2][2];
    #pragma unroll
    for (int j = 0; j < 2; ++j) {
      acc[j][0] = (f32x4){0.f, 0.f, 0.f, 0.f};
      acc[j][1] = (f32x4){0.f, 0.f, 0.f, 0.f};
    }
    __builtin_amdgcn_s_setprio(1);
    #pragma unroll
    for (int k = 0; k < 8; ++k) {
      const int col = k * 16 + g4 * 4;
      bf16x8 a0 = *(const bf16x8*)&bufR[base0 + (col ^ sw0)];
      bf16x8 a1 = *(const bf16x8*)&bufR[base1 + (col ^ sw1)];
      acc[0][0] = __builtin_amdgcn_mfma_f32_16x16x32_bf16(a0, Bf[0][k], acc[0][0], 0, 0, 0);
      acc[0][1] = __builtin_amdgcn_mfma_f32_16x16x32_bf16(a1, Bf[0][k], acc[0][1], 0, 0, 0);
      acc[1][0] = __builtin_amdgcn_mfma_f32_16x16x32_bf16(a0, Bf[1][k], acc[1][0], 0, 0, 0);
      acc[1][1] = __builtin_amdgcn_mfma_f32_16x16x32_bf16(a1, Bf[1][k], acc[1][1], 0, 0, 0);
    }
    __builtin_amdgcn_s_setprio(0);

    // ---- fixed-max softmax + soft-argmax ----
    const int rb = iter * 64 + lr0;
    #pragma unroll
    for (int s = 0; s < 2; ++s) {
      #pragma unroll
      for (int e = 0; e < 4; ++e) {
        const int r  = rb + s * 16 + e;            // < 1600
        const int vl = (r * 6554) >> 21;           // == r / 320
        const float vf = (float)(chunk * 5 + vl);
        const float uf = (float)(r - vl * 320);
        #pragma unroll
        for (int j = 0; j < 2; ++j) {
          const float ev = fexp2(fmaf(K2_, acc[j][s][e], MOFF_));
          stS[j] += ev;
          stU[j] = fmaf(ev, uf, stU[j]);
          stV[j] = fmaf(ev, vf, stV[j]);
        }
      }
    }

    // ---- all waves done reading bufR; refill it with tile iter+2; counted wait for iter+1 ----
    __builtin_amdgcn_s_barrier();
    if (iter + 2 < ITERS_) {
      const uint32_t* s = PNp + ((size_t)(iter + 2) << 13);
      uint32_t* d = ldsw + (iter & 1) * 8192;
      #pragma unroll
      for (int jj = 0; jj < 4; ++jj) dma16(s + jj * 256, d + jj * 256);
      asm volatile("s_waitcnt vmcnt(4)" ::: "memory");   // own (iter+1) loads done
    } else if (iter + 1 < ITERS_) {
      asm volatile("s_waitcnt vmcnt(0)" ::: "memory");   // tail: last tile drain
    }
    __builtin_amdgcn_sched_barrier(0);
    __builtin_amdgcn_s_barrier();                        // all waves' (iter+1) loads done
  }

  // ---- merge the 4 g4-groups (disjoint px subsets, same n) ----
  #pragma unroll
  for (int j = 0; j < 2; ++j) {
    float S = stS[j], U = stU[j], V = stV[j];
    S += __shfl_xor(S, 16, 64); U += __shfl_xor(U, 16, 64); V += __shfl_xor(V, 16, 64);
    S += __shfl_xor(S, 32, 64); U += __shfl_xor(U, 32, 64); V += __shfl_xor(V, 32, 64);
    if (lane < 16) {
      const int n = nbase + j * 16 + l15;
      partials[((size_t)(p * CHUNKS_ + chunk) * 2 + h) * N_ + n] = make_float4(S, U, V, 0.f);
    }
  }
}

// ---------------- kernel 3: sum 128 partials per (p, n) -> coords; ids ----------------
__global__ void k_final(const float4* __restrict__ partials, float* __restrict__ out) {
  const int t = blockIdx.x * blockDim.x + threadIdx.x;   // 0..2047
  const int p = t >> 10, n = t & 1023;
  float S = 0.f, U = 0.f, V = 0.f;
  #pragma unroll 4
  for (int s = 0; s < 2 * CHUNKS_; ++s) {
    const float4 v = partials[((size_t)p * 2 * CHUNKS_ + s) * N_ + n];
    S += v.x; U += v.y; V += v.z;
  }
  out[(size_t)(p * N_ + n) * 2 + 0] = U / S;
  out[(size_t)(p * N_ + n) * 2 + 1] = V / S;
  if (t < 4) {
    const float ids[4] = {1.f, 3.f, 0.f, 2.f};  // tgt_ids then src_ids
    out[6144 + t] = ids[t];
  }
}

// ---------------- host launch ----------------
extern "C" void kernel_launch(void* const* d_in, const int* in_sizes, int n_in,
                              void* d_out, int out_size, void* d_ws, size_t ws_size,
                              hipStream_t stream) {
  const float* kscores = (const float*)d_in[0];   // (4,1,1024)
  const float* kdesc   = (const float*)d_in[1];   // (4,256,1024)
  const float* dense   = (const float*)d_in[2];   // (4,256,320,320)
  float* out = (float*)d_out;

  char* ws = (char*)d_ws;
  uint16_t* tgt = (uint16_t*)(ws + WS_TGT_OFF);
  float4*   par = (float4*)(ws + WS_PAR_OFF);
  uint32_t* PN  = (uint32_t*)(ws + WS_PN_OFF);

  k_pre<<<P_ * TILES_ + (P_ * N_) / 256, 256, 0, stream>>>(dense, kdesc, kscores, PN, tgt, out);
  k_main<<<P_ * NB_ * CHUNKS_, 512, 0, stream>>>(PN, tgt, par);
  k_final<<<(P_ * N_) / 256, 256, 0, stream>>>(par, out);
}

// Round 7
// 189.204 us; speedup vs baseline: 1.2843x; 1.2843x over previous
//
#include <hip/hip_runtime.h>
#include <stdint.h>

// ---------------- problem constants ----------------
#define HW_      102400          // 320*320
#define C_       256
#define N_       1024
#define P_       2               // pairs
#define TILES_   1600            // 64-px tiles per src plane
#define CHUNKS_  32              // chunks per (pair, n-block)
#define ITERS_   50              // 50 tiles of 64 px = 3200 px = 10 image rows per chunk
#define NB_      4               // n-blocks of 256 keypoints
#define K2_      144.269504088896340f   // 100 / ln(2)
#define MOFF_    (-72.134752044448170f) // -K2_ * 0.5 (fixed softmax max; cosine logits <= ~1.02)

typedef __attribute__((ext_vector_type(8))) short bf16x8;
typedef __attribute__((ext_vector_type(4))) float f32x4;

// ws layout (bytes):
//   tgt bf16 : [0, 1MB)       2*1024*256 bf16, [p][n][c]
//   partials : [1MB, 3MB)     2*32*2*1024 float4 (S,U,V,-)
//   PN       : [4MB, +105MB)  normalized src bf16, [p][tile][r][dphys] dwords,
//              dphys group g' = g ^ SWR(r) (4-dword groups); dword = ch pair (2d,2d+1)
#define WS_TGT_OFF  0
#define WS_PAR_OFF  (1u << 20)
#define WS_PN_OFF   (4u << 20)

#define SWR(r) (((r) ^ ((r) >> 3)) & 7)   // per-row XOR swizzle (4-dword groups)

__device__ __forceinline__ uint32_t packbf(float a, float b) {
  uint32_t r;
  asm("v_cvt_pk_bf16_f32 %0, %1, %2" : "=v"(r) : "v"(a), "v"(b));
  return r;
}
__device__ __forceinline__ float fexp2(float x) {
  return __builtin_amdgcn_exp2f(x);
}
__device__ __forceinline__ void dma16(const uint32_t* g, uint32_t* l) {
  // async global->LDS, 16B/lane; LDS dest = wave-uniform base + lane*16
  __builtin_amdgcn_global_load_lds(
      (const __attribute__((address_space(1))) uint32_t*)g,
      (__attribute__((address_space(3))) uint32_t*)l, 16, 0, 0);
}

// ---------------- kernel 1: (a) prenorm dense -> PN (bf16, swizzled, float4 loads);
// ----------------           (b) tgt normalize -> bf16; copy weights ----------------
__global__ __launch_bounds__(256)
void k_pre(const float* __restrict__ dense, const float* __restrict__ kdesc,
           const float* __restrict__ kscores, uint32_t* __restrict__ PN,
           uint16_t* __restrict__ tgt, float* __restrict__ out) {
  __shared__ float part[16][64];
  __shared__ float sinv[64];
  __shared__ uint32_t T[8192];     // one 64px x 256ch bf16 tile, swizzled
  const int bid = blockIdx.x;
  if (bid < P_ * TILES_) {
    const int p = bid / TILES_, tile = bid % TILES_;
    const int t   = threadIdx.x;
    const int px4 = (t & 15) * 4;          // 4 consecutive px
    const int cg  = t >> 4;                // 16 ch-groups of 16 ch
    const float* src = dense + (size_t)(p * 2) * C_ * HW_ + (size_t)(cg * 16) * HW_
                     + tile * 64 + px4;    // src ids 0,2
    // ---- pass 1: float4 loads (1KB/wave-instr), keep all 64 values in regs ----
    float v[16][4];
    #pragma unroll
    for (int cc = 0; cc < 16; ++cc) {
      const float4 q = *(const float4*)(src + (size_t)cc * HW_);
      v[cc][0] = q.x; v[cc][1] = q.y; v[cc][2] = q.z; v[cc][3] = q.w;
    }
    float ps[4] = {0.f, 0.f, 0.f, 0.f};
    #pragma unroll
    for (int cc = 0; cc < 16; ++cc) {
      #pragma unroll
      for (int i = 0; i < 4; ++i) ps[i] = fmaf(v[cc][i], v[cc][i], ps[i]);
    }
    #pragma unroll
    for (int i = 0; i < 4; ++i) part[cg][px4 + i] = ps[i];
    __syncthreads();
    if (t < 64) {
      float s = 0.f;
      #pragma unroll
      for (int g = 0; g < 16; ++g) s += part[g][t];
      sinv[t] = 1.f / fmaxf(sqrtf(s), 1e-12f);
    }
    __syncthreads();
    // ---- scale + pack + swizzled LDS tile ----
    #pragma unroll
    for (int i = 0; i < 4; ++i) {
      const int r  = px4 + i;
      const float iv = sinv[r];
      const int s8 = SWR(r);
      uint32_t* dst = &T[r * 128];
      uint4 A, B;
      A.x = packbf(v[0][i] * iv,  v[1][i] * iv);
      A.y = packbf(v[2][i] * iv,  v[3][i] * iv);
      A.z = packbf(v[4][i] * iv,  v[5][i] * iv);
      A.w = packbf(v[6][i] * iv,  v[7][i] * iv);
      B.x = packbf(v[8][i] * iv,  v[9][i] * iv);
      B.y = packbf(v[10][i] * iv, v[11][i] * iv);
      B.z = packbf(v[12][i] * iv, v[13][i] * iv);
      B.w = packbf(v[14][i] * iv, v[15][i] * iv);
      *(uint4*)&dst[((2 * cg + 0) ^ s8) * 4] = A;
      *(uint4*)&dst[((2 * cg + 1) ^ s8) * 4] = B;
    }
    __syncthreads();
    // ---- linear coalesced writeout (dwordx4 both sides) ----
    uint32_t* dstg = PN + ((size_t)(p * TILES_ + tile) << 13) + t * 32;
    #pragma unroll
    for (int k = 0; k < 8; ++k)
      *(uint4*)&dstg[k * 4] = *(const uint4*)&T[t * 32 + k * 4];
  } else {
    // ---- tgt keypoint descriptors -> normalized bf16 [p][n][c]; copy weights ----
    const int t = (bid - P_ * TILES_) * 256 + threadIdx.x;   // 0..2047
    const int p = t >> 10, n = t & 1023;
    const float* src = kdesc + (size_t)(p * 2 + 1) * C_ * N_ + n;   // tgt ids 1,3
    float s = 0.f;
    #pragma unroll 16
    for (int c = 0; c < C_; ++c) { const float v2 = src[c * N_]; s = fmaf(v2, v2, s); }
    const float inv = 1.f / fmaxf(sqrtf(s), 1e-12f);
    uint32_t* dst = (uint32_t*)(tgt + (size_t)t * C_);
    #pragma unroll 4
    for (int c8 = 0; c8 < C_; c8 += 8) {
      uint4 wv;
      wv.x = packbf(src[(c8 + 0) * N_] * inv, src[(c8 + 1) * N_] * inv);
      wv.y = packbf(src[(c8 + 2) * N_] * inv, src[(c8 + 3) * N_] * inv);
      wv.z = packbf(src[(c8 + 4) * N_] * inv, src[(c8 + 5) * N_] * inv);
      wv.w = packbf(src[(c8 + 6) * N_] * inv, src[(c8 + 7) * N_] * inv);
      *(uint4*)&dst[c8 / 2] = wv;
    }
    out[4096 + t] = kscores[(p * 2 + 1) * N_ + n];   // match_weights
  }
}

// ---------------- kernel 2: DMA-staged QK^T + fixed-max softmax + soft-argmax ----------------
// block: 1024 thr (16 waves = 2(h) x 8(q)); 256 keypoints x 3200 px chunk.
// grid: 256 = EXACTLY 1 block/CU (64KB LDS, <=128 VGPR), single dispatch round.
// One __syncthreads per iter; next tile's DMA issued at loop top (full-iter issue-to-drain).
// The 4 blocks sharing a (p,chunk) map to the SAME XCD -> PN read from L2 (verified R3/R4).
__global__ __launch_bounds__(1024, 4)
void k_main(const uint32_t* __restrict__ PN, const uint16_t* __restrict__ tgt,
            float4* __restrict__ partials) {
  __shared__ uint32_t lds[2 * 8192];   // 2 bufs x (64 px x 256 bf16) = 64 KB

  // ---- XCD co-locating decode: same (p,chunk) -> bids {x, x+8, x+16, x+24} ----
  const int bid = blockIdx.x;              // 0..255
  const int xcd = bid & 7;
  const int rr  = bid >> 3;                // 0..31
  const int nb  = rr & 3;
  const int grp = xcd + 8 * (rr >> 2);     // 0..63 = (p, chunk)
  const int p     = grp >> 5;
  const int chunk = grp & 31;

  const int t    = threadIdx.x;
  const int lane = t & 63;
  const int w    = t >> 6;                 // 0..15
  const int l15  = lane & 15;
  const int g4   = lane >> 4;
  const int h    = w & 1;                  // px half (32 rows)
  const int q    = w >> 1;                 // n slice (32 n)

  // ---- B fragments (tgt, [n][c] bf16): 2 j-tiles x 8 k-slices = 64 VGPR ----
  bf16x8 Bf[2][8];
  const int nbase = nb * 256 + q * 32;
  #pragma unroll
  for (int j = 0; j < 2; ++j) {
    const uint16_t* tp = tgt + (size_t)(p * N_ + nbase + j * 16 + l15) * C_ + g4 * 8;
    #pragma unroll
    for (int k = 0; k < 8; ++k) Bf[j][k] = *(const bf16x8*)(tp + k * 32);
  }

  float stS[2], stU[2], stV[2];
  #pragma unroll
  for (int j = 0; j < 2; ++j) { stS[j] = 0.f; stU[j] = 0.f; stV[j] = 0.f; }

  const int row0  = h * 32 + l15;
  const int sw0   = SWR(row0) << 2;
  const int sw1   = sw0 ^ 8;               // SWR(row+16) = SWR(row)^2
  const int base0 = row0 * 128;
  const int base1 = base0 + 16 * 128;
  const int lr0   = h * 32 + g4 * 4;       // acc px-row base (s=0)

  // static u-offsets within a 64-px tile (tile always inside ONE image row: 320 = 5*64)
  float offf[2][4];
  #pragma unroll
  for (int s = 0; s < 2; ++s)
    #pragma unroll
    for (int e = 0; e < 4; ++e) offf[s][e] = (float)(lr0 + s * 16 + e);

  // DMA: wave w stages 2KB of the 32KB tile
  const uint32_t* PNp = PN + ((size_t)(p * TILES_ + chunk * ITERS_) << 13) + w * 512 + lane * 4;
  uint32_t* ldsw0 = &lds[w * 512];

  // ---- prologue: stage tile 0 into buf 0 ----
  dma16(PNp, ldsw0);
  dma16(PNp + 256, ldsw0 + 256);
  __syncthreads();

  float u0f = 0.f, v0f = (float)(chunk * 10);
  for (int iter = 0; iter < ITERS_; ++iter) {
    // ---- issue next tile's DMA (drained by this iter's ending __syncthreads) ----
    if (iter + 1 < ITERS_) {
      const uint32_t* s = PNp + ((size_t)(iter + 1) << 13);
      uint32_t* d = ldsw0 + ((iter & 1) ^ 1) * 8192;
      dma16(s, d);
      dma16(s + 256, d + 256);
    }

    // ---- MFMA from current buffer ----
    const uint32_t* bufR = &lds[(iter & 1) * 8192];
    f32x4 acc[2][2];
    #pragma unroll
    for (int j = 0; j < 2; ++j) {
      acc[j][0] = (f32x4){0.f, 0.f, 0.f, 0.f};
      acc[j][1] = (f32x4){0.f, 0.f, 0.f, 0.f};
    }
    __builtin_amdgcn_s_setprio(1);
    #pragma unroll
    for (int k = 0; k < 8; ++k) {
      const int col = k * 16 + g4 * 4;
      bf16x8 a0 = *(const bf16x8*)&bufR[base0 + (col ^ sw0)];
      bf16x8 a1 = *(const bf16x8*)&bufR[base1 + (col ^ sw1)];
      acc[0][0] = __builtin_amdgcn_mfma_f32_16x16x32_bf16(a0, Bf[0][k], acc[0][0], 0, 0, 0);
      acc[0][1] = __builtin_amdgcn_mfma_f32_16x16x32_bf16(a1, Bf[0][k], acc[0][1], 0, 0, 0);
      acc[1][0] = __builtin_amdgcn_mfma_f32_16x16x32_bf16(a0, Bf[1][k], acc[1][0], 0, 0, 0);
      acc[1][1] = __builtin_amdgcn_mfma_f32_16x16x32_bf16(a1, Bf[1][k], acc[1][1], 0, 0, 0);
    }
    __builtin_amdgcn_s_setprio(0);

    // ---- fixed-max softmax + soft-argmax (v constant per tile; u = u0 + off) ----
    #pragma unroll
    for (int j = 0; j < 2; ++j) {
      float tS = 0.f, tU = 0.f;
      #pragma unroll
      for (int s = 0; s < 2; ++s) {
        #pragma unroll
        for (int e = 0; e < 4; ++e) {
          const float ev = fexp2(fmaf(K2_, acc[j][s][e], MOFF_));
          tS += ev;
          tU = fmaf(ev, offf[s][e], tU);
        }
      }
      stS[j] += tS;
      stU[j] += fmaf(u0f, tS, tU);
      stV[j] = fmaf(v0f, tS, stV[j]);
    }
    u0f += 64.f;
    if (u0f > 290.f) { u0f = 0.f; v0f += 1.f; }   // u0 cycles 0,64,128,192,256

    __syncthreads();   // drains this iter's DMAs (issued a full iter ago) + publishes
  }

  // ---- merge the 4 g4-groups (disjoint px subsets, same n) ----
  #pragma unroll
  for (int j = 0; j < 2; ++j) {
    float S = stS[j], U = stU[j], V = stV[j];
    S += __shfl_xor(S, 16, 64); U += __shfl_xor(U, 16, 64); V += __shfl_xor(V, 16, 64);
    S += __shfl_xor(S, 32, 64); U += __shfl_xor(U, 32, 64); V += __shfl_xor(V, 32, 64);
    if (lane < 16) {
      const int n = nbase + j * 16 + l15;
      partials[((size_t)(p * CHUNKS_ + chunk) * 2 + h) * N_ + n] = make_float4(S, U, V, 0.f);
    }
  }
}

// ---------------- kernel 3: sum 64 partials per (p, n) -> coords; ids ----------------
__global__ void k_final(const float4* __restrict__ partials, float* __restrict__ out) {
  const int t = blockIdx.x * blockDim.x + threadIdx.x;   // 0..2047
  const int p = t >> 10, n = t & 1023;
  float S = 0.f, U = 0.f, V = 0.f;
  #pragma unroll 4
  for (int s = 0; s < 2 * CHUNKS_; ++s) {
    const float4 v = partials[((size_t)p * 2 * CHUNKS_ + s) * N_ + n];
    S += v.x; U += v.y; V += v.z;
  }
  out[(size_t)(p * N_ + n) * 2 + 0] = U / S;
  out[(size_t)(p * N_ + n) * 2 + 1] = V / S;
  if (t < 4) {
    const float ids[4] = {1.f, 3.f, 0.f, 2.f};  // tgt_ids then src_ids
    out[6144 + t] = ids[t];
  }
}

// ---------------- host launch ----------------
extern "C" void kernel_launch(void* const* d_in, const int* in_sizes, int n_in,
                              void* d_out, int out_size, void* d_ws, size_t ws_size,
                              hipStream_t stream) {
  const float* kscores = (const float*)d_in[0];   // (4,1,1024)
  const float* kdesc   = (const float*)d_in[1];   // (4,256,1024)
  const float* dense   = (const float*)d_in[2];   // (4,256,320,320)
  float* out = (float*)d_out;

  char* ws = (char*)d_ws;
  uint16_t* tgt = (uint16_t*)(ws + WS_TGT_OFF);
  float4*   par = (float4*)(ws + WS_PAR_OFF);
  uint32_t* PN  = (uint32_t*)(ws + WS_PN_OFF);

  k_pre<<<P_ * TILES_ + (P_ * N_) / 256, 256, 0, stream>>>(dense, kdesc, kscores, PN, tgt, out);
  k_main<<<P_ * NB_ * CHUNKS_, 1024, 0, stream>>>(PN, tgt, par);
  k_final<<<(P_ * N_) / 256, 256, 0, stream>>>(par, out);
}